// Round 10
// baseline (54.164 us; speedup 1.0000x reference)
//
#include <hip/hip_runtime.h>
#include <hip/hip_bf16.h>

#define BSZ 16
#define TT 512
#define DD 512
#define MM (BSZ * TT)          // 8192 rows for the GEMM
#define NPART 8                // partial slices: 8 col-tiles of 64
#define NMEGA 1024             // mega blocks: 4 waves each (2 GEMM + 2 LR)

typedef __attribute__((ext_vector_type(8))) short bf16x8;
typedef __attribute__((ext_vector_type(4))) float f32x4;

// ================= prep: convert_w + cumsum->imap (272 blocks, ~2 us) =================
__global__ __launch_bounds__(256) void prep_kernel(const float* __restrict__ W1,
                                                   const int* __restrict__ target,
                                                   ushort* __restrict__ wth,
                                                   int* __restrict__ imap, int L) {
    int bid = blockIdx.x;
    if (bid < 256) {
        // ---- convert_w: W1[k][n] -> wth[n][k] (transposed bf16) ----
        int t = bid * 256 + threadIdx.x;
        int n  = t & (DD - 1);
        int kq = t >> 9;
        ushort hh[4];
        #pragma unroll
        for (int i = 0; i < 4; ++i) {
            float f = W1[(size_t)(kq * 4 + i) * DD + n];
            __hip_bfloat16 bh = __float2bfloat16(f);
            hh[i] = *(ushort*)&bh;
        }
        ((ushort4*)wth)[(size_t)n * (DD / 4) + kq] = make_ushort4(hh[0], hh[1], hh[2], hh[3]);
    } else {
        // ---- cumsum (256 thr x 2 elems) then scatter frame->phoneme index map ----
        int b = bid - 256;
        __shared__ int s[TT];
        int t = threadIdx.x;
        s[t]       = target[b * TT + t];
        s[t + 256] = target[b * TT + t + 256];
        __syncthreads();
        #pragma unroll
        for (int off = 1; off < TT; off <<= 1) {
            int v0 = (t >= off) ? s[t - off] : 0;
            int v1 = s[t + 256 - off];
            __syncthreads();
            s[t] += v0;
            s[t + 256] += v1;
            __syncthreads();
        }
        int total = s[TT - 1];
        int* imb = imap + (size_t)b * L;
        for (int ph = t; ph < TT; ph += 256) {
            int st = (ph == 0) ? 0 : s[ph - 1];
            int en = s[ph];
            for (int d = st; d < en; ++d) imb[d] = ph;
        }
        for (int l = total + t; l < L; l += 256) imb[l] = -1;
    }
}

// ================= mega: wave-specialized, zero LDS, zero barriers =================
// 1024 blocks x 4 waves. Waves 0-1: GEMM (32x64 tile each, A from fp32 x with
// in-register bf16 cvt, B from L2-resident wth, frags straight from global -> no
// LDS, no syncthreads). Waves 2-3: LR streaming (broadcast idx, coalesced 1KB
// gathers from L3-resident x, nontemporal stores). MFMA pipe and VMEM pipe
// co-schedule on each SIMD (m114); GEMM (~2-3us of work) hides entirely under
// LR's ~21us of mandatory HBM writes.
__global__ __launch_bounds__(256, 4) void mega_kernel(const ushort* __restrict__ wth,
                                                      const float* __restrict__ b1,
                                                      const float* __restrict__ W2,
                                                      const float* __restrict__ x,
                                                      const int* __restrict__ imap,
                                                      float* __restrict__ out,
                                                      float* __restrict__ partial,
                                                      int L) {
    const int bid = blockIdx.x;
    const int t = threadIdx.x;
    const int lane = t & 63, wave = t >> 6;

    if (wave >= 2) {
        // ---------------- LR role: 32 full rows per wave ----------------
        const int h = bid * 2 + (wave - 2);          // 0..2047
        const int b_lr = h >> 7;                     // 16 batches x 128 waves
        const int chunk = (h & 127) * 32;
        const f32x4* x4g = (const f32x4*)(x + (size_t)b_lr * TT * DD);
        f32x4*       o4  = (f32x4*)(out + (size_t)b_lr * L * DD);
        const int*   imb = imap + (size_t)b_lr * L;
        #pragma unroll 2
        for (int r = 0; r < 32; ++r) {
            int l = chunk + r;
            int idx = imb[l];                        // broadcast (1 transaction)
            f32x4 g0, g1;
            if (idx >= 0) {
                g0 = x4g[(size_t)idx * 128 + lane];
                g1 = x4g[(size_t)idx * 128 + 64 + lane];
            } else {
                g0 = (f32x4){0.f, 0.f, 0.f, 0.f};
                g1 = g0;
            }
            __builtin_nontemporal_store(g0, &o4[(size_t)l * 128 + lane]);
            __builtin_nontemporal_store(g1, &o4[(size_t)l * 128 + 64 + lane]);
        }
        return;
    }

    // ---------------- GEMM role: one 32x64 tile per wave ----------------
    const int g = bid * 2 + wave;                    // 0..2047
    const int rt = g >> 3, ct = g & 7;
    const int row0 = rt * 32, col0 = ct * 64;
    const int l15 = lane & 15, l4 = lane >> 4;
    f32x4 acc[2][4] = {};

    #pragma unroll 2
    for (int kt = 0; kt < DD / 32; ++kt) {
        const int k0 = kt * 32;
        // A-frags: load 8 fp32 of row (row0+i*16+l15), k-chunk l4*8; cvt to bf16
        bf16x8 af[2];
        #pragma unroll
        for (int i = 0; i < 2; ++i) {
            const float* xa = x + (size_t)(row0 + i * 16 + l15) * DD + k0 + l4 * 8;
            f32x4 f0 = ((const f32x4*)xa)[0];
            f32x4 f1 = ((const f32x4*)xa)[1];
            ushort us[8];
            #pragma unroll
            for (int e = 0; e < 4; ++e) {
                __hip_bfloat16 h0 = __float2bfloat16(f0[e]);
                __hip_bfloat16 h1 = __float2bfloat16(f1[e]);
                us[e] = *(ushort*)&h0;
                us[e + 4] = *(ushort*)&h1;
            }
            af[i] = *(bf16x8*)us;
        }
        // B-frags: straight 16B loads from wth[n][k] (L2-resident)
        bf16x8 bf[4];
        #pragma unroll
        for (int j = 0; j < 4; ++j)
            bf[j] = *(const bf16x8*)&wth[(size_t)(col0 + j * 16 + l15) * DD + k0 + l4 * 8];
        #pragma unroll
        for (int i = 0; i < 2; ++i)
            #pragma unroll
            for (int j = 0; j < 4; ++j)
                acc[i][j] = __builtin_amdgcn_mfma_f32_16x16x32_bf16(af[i], bf[j], acc[i][j], 0, 0, 0);
    }

    // epilogue: relu(acc + b1) dot W2 over this wave's 64 cols; slice = ct
    #pragma unroll
    for (int i = 0; i < 2; ++i) {
        #pragma unroll
        for (int r = 0; r < 4; ++r) {
            float s = 0.f;
            #pragma unroll
            for (int j = 0; j < 4; ++j) {
                int cg = col0 + j * 16 + l15;
                float h = acc[i][j][r] + b1[cg];
                h = fmaxf(h, 0.f);
                s += h * W2[cg];
            }
            s += __shfl_xor(s, 1);
            s += __shfl_xor(s, 2);
            s += __shfl_xor(s, 4);
            s += __shfl_xor(s, 8);
            if (l15 == 0) {
                int rg = row0 + i * 16 + l4 * 4 + r;
                partial[(size_t)ct * MM + rg] = s;
            }
        }
    }
}

// ---------------- final dpo: relu(sum of 8 partials + b2) ----------------
__global__ __launch_bounds__(256) void dpo_kernel(const float* __restrict__ partial,
                                                  const float* __restrict__ b2,
                                                  float* __restrict__ dpo) {
    int m = blockIdx.x * 256 + threadIdx.x;
    float s = b2[0];
    #pragma unroll
    for (int nb = 0; nb < NPART; ++nb) s += partial[(size_t)nb * MM + m];
    dpo[m] = fmaxf(s, 0.f);
}

extern "C" void kernel_launch(void* const* d_in, const int* in_sizes, int n_in,
                              void* d_out, int out_size, void* d_ws, size_t ws_size,
                              hipStream_t stream) {
    const float* x      = (const float*)d_in[0];
    const float* W1     = (const float*)d_in[1];
    const float* b1     = (const float*)d_in[2];
    const float* W2     = (const float*)d_in[3];
    const float* b2     = (const float*)d_in[4];
    const int*   target = (const int*)d_in[5];
    int L = (out_size - BSZ * TT) / (BSZ * DD);   // = 4096

    float* out_lr  = (float*)d_out;                        // [B, L, D]
    float* out_dpo = (float*)d_out + (size_t)BSZ * L * DD; // [B, T]

    // ws layout
    ushort* wth     = (ushort*)d_ws;                        // 512 KiB
    float*  partial = (float*)(wth + (size_t)DD * DD);      // 8*8192 floats
    int*    imap    = (int*)(partial + (size_t)NPART * MM); // 16*4096 ints

    prep_kernel<<<dim3(272), dim3(256), 0, stream>>>(W1, target, wth, imap, L);
    mega_kernel<<<dim3(NMEGA), dim3(256), 0, stream>>>(wth, b1, W2, x, imap,
                                                       out_lr, partial, L);
    dpo_kernel<<<dim3(MM / 256), dim3(256), 0, stream>>>(partial, b2, out_dpo);
}

// Round 11
// 42.230 us; speedup vs baseline: 1.2826x; 1.2826x over previous
//
#include <hip/hip_runtime.h>
#include <hip/hip_bf16.h>

#define BSZ 16
#define TT 512
#define DD 512
#define MM (BSZ * TT)          // 8192 rows for the GEMM
#define NPART 8                // partial slices: 4 col-blocks x 2 col-halves
#define NMEGA 512              // mega blocks: 128 row-tiles x 4 col-tiles

typedef __attribute__((ext_vector_type(8))) short bf16x8;
typedef __attribute__((ext_vector_type(8))) unsigned short ushort8;
typedef __attribute__((ext_vector_type(4))) float f32x4;

// ================= prep: convert_w + cumsum->imap (272 blocks, ~1-2 us) =================
__global__ __launch_bounds__(256) void prep_kernel(const float* __restrict__ W1,
                                                   const int* __restrict__ target,
                                                   ushort* __restrict__ wth,
                                                   int* __restrict__ imap, int L) {
    int bid = blockIdx.x;
    if (bid < 256) {
        // ---- convert_w: W1[k][n] -> wth[n][k] (transposed bf16) ----
        int t = bid * 256 + threadIdx.x;
        int n  = t & (DD - 1);
        int kq = t >> 9;
        ushort hh[4];
        #pragma unroll
        for (int i = 0; i < 4; ++i) {
            float f = W1[(size_t)(kq * 4 + i) * DD + n];
            __hip_bfloat16 bh = __float2bfloat16(f);
            hh[i] = *(ushort*)&bh;
        }
        ((ushort4*)wth)[(size_t)n * (DD / 4) + kq] = make_ushort4(hh[0], hh[1], hh[2], hh[3]);
    } else {
        // ---- cumsum (256 thr x 2 elems) then scatter frame->phoneme index map ----
        int b = bid - 256;
        __shared__ int s[TT];
        int t = threadIdx.x;
        s[t]       = target[b * TT + t];
        s[t + 256] = target[b * TT + t + 256];
        __syncthreads();
        #pragma unroll
        for (int off = 1; off < TT; off <<= 1) {
            int v0 = (t >= off) ? s[t - off] : 0;
            int v1 = s[t + 256 - off];
            __syncthreads();
            s[t] += v0;
            s[t + 256] += v1;
            __syncthreads();
        }
        int total = s[TT - 1];
        int* imb = imap + (size_t)b * L;
        for (int ph = t; ph < TT; ph += 256) {
            int st = (ph == 0) ? 0 : s[ph - 1];
            int en = s[ph];
            for (int d = st; d < en; ++d) imb[d] = ph;
        }
        for (int l = total + t; l < L; l += 256) imb[l] = -1;
    }
}

// ================= mega: bf16 MFMA GEMM (64x128 tile, BK=64) + pipelined LR =========
// Round-8 skeleton (best validated: 43.0us) + 2-deep LR software pipeline:
//   - idx loads for step k+1 issue during step k (post-MFMA) -> gathers never wait
//   - stores for step k issue right AFTER barrier k -> drain at barrier k+1 with a
//     full K-step of compute to cover the store-ack latency
// 512 blocks, 48 KB LDS -> 2 blocks/CU; A reg-staged from fp32 x, B via
// global_load_lds (inverse-swizzled source), XOR-swizzled LDS, nt LR stores.
#define BM 64
#define BN 128
#define BK 64
__global__ __launch_bounds__(256, 2) void mega_kernel(const ushort* __restrict__ wth,
                                                      const float* __restrict__ b1,
                                                      const float* __restrict__ W2,
                                                      const float* __restrict__ x,
                                                      const int* __restrict__ imap,
                                                      float* __restrict__ out,
                                                      float* __restrict__ partial,
                                                      int L) {
    __shared__ ushort ldsA[2][BM * 64];   // [buf][row*64 + slot*8 + e] = 2x8 KB
    __shared__ ushort ldsB[2][BN * 64];   // 2x16 KB; total 48 KB
    const int bid = blockIdx.x;
    const int t = threadIdx.x;
    const int lane = t & 63, wave = t >> 6;
    const int row0 = (bid >> 2) * BM;
    const int col0 = (bid & 3) * BN;
    const int rq = t >> 3;                   // 0..31: row within a 32-row B chunk
    const int ls = (t & 7) ^ (rq & 7);       // logical slot this lane must FETCH (B)
    const int sco = ls * 8;                  // k-subcolumn (ushorts)
    const int ar = t >> 2;                   // 0..63: A row this thread stages
    const int ac = (t & 3) * 16;             // 16-float k-chunk within A row

    // LR assignment: same batch as this tile's A-rows (L2 locality)
    const int b_lr    = bid >> 5;
    const int chunk0  = (bid & 31) * 128;
    const int lr_lane = t & 127;             // f32x4 index within a 512-float row
    const int lr_half = t >> 7;              // 0/1
    const f32x4* x4g = (const f32x4*)(x + (size_t)b_lr * TT * DD);
    f32x4*       o4  = (f32x4*)(out + (size_t)b_lr * L * DD);
    const int*   imb = imap + (size_t)b_lr * L;

    auto stageB = [&](int buf, int kt) {
        const int k0 = kt * BK;
        #pragma unroll
        for (int q = 0; q < 4; ++q) {
            int row = q * 32 + rq;
            const ushort* gb = wth + (size_t)(col0 + row) * DD + k0 + sco;
            auto lb = (__attribute__((address_space(3))) unsigned int*)
                      ((char*)&ldsB[buf][0] + q * 4096 + wave * 1024);
            __builtin_amdgcn_global_load_lds(
                (const __attribute__((address_space(1))) unsigned int*)gb, lb, 16, 0, 0);
        }
    };
    auto stageA = [&](int buf, int kt) {
        const float* xa = x + (size_t)(row0 + ar) * DD + kt * BK + ac;
        float fl[16];
        *(f32x4*)&fl[0]  = ((const f32x4*)xa)[0];
        *(f32x4*)&fl[4]  = ((const f32x4*)xa)[1];
        *(f32x4*)&fl[8]  = ((const f32x4*)xa)[2];
        *(f32x4*)&fl[12] = ((const f32x4*)xa)[3];
        ushort us[16];
        #pragma unroll
        for (int j = 0; j < 16; ++j) {
            __hip_bfloat16 bh = __float2bfloat16(fl[j]);
            us[j] = *(ushort*)&bh;
        }
        int s0 = ((t & 3) * 2)     ^ (ar & 7);
        int s1 = ((t & 3) * 2 + 1) ^ (ar & 7);
        *(ushort8*)&ldsA[buf][ar * 64 + s0 * 8] = *(ushort8*)&us[0];
        *(ushort8*)&ldsA[buf][ar * 64 + s1 * 8] = *(ushort8*)&us[8];
    };

    const int wm = (wave >> 1) * 32;   // wave row offset within 64-row tile
    const int wn = (wave & 1) * 64;    // wave col offset within 128-col tile
    const int l15 = lane & 15, l4 = lane >> 4;
    f32x4 acc[2][4] = {};

    // LR pipeline state: idx for current step (prefetched), gv pending store
    int idxc[8];
    {
        const int rb = chunk0 + lr_half;
        #pragma unroll
        for (int p = 0; p < 8; ++p) idxc[p] = imb[rb + p * 2];
    }
    f32x4 gv[8];

    stageB(0, 0);
    stageA(0, 0);
    __syncthreads();
    int cur = 0;
    #pragma unroll 1
    for (int kt = 0; kt < DD / BK; ++kt) {
        // ---- LR stores of PREVIOUS step (drain at this iter's barrier, fully hidden) ----
        if (kt > 0) {
            const int rbp = chunk0 + (kt - 1) * 16 + lr_half;
            #pragma unroll
            for (int p = 0; p < 8; ++p)
                __builtin_nontemporal_store(gv[p], &o4[(size_t)(rbp + p * 2) * (DD / 4) + lr_lane]);
        }
        if (kt + 1 < DD / BK) stageB(cur ^ 1, kt + 1);

        // ---- LR gathers for THIS step (idx already in registers) ----
        #pragma unroll
        for (int p = 0; p < 8; ++p)
            gv[p] = (idxc[p] >= 0) ? x4g[(size_t)idxc[p] * (DD / 4) + lr_lane]
                                   : (f32x4){0.f, 0.f, 0.f, 0.f};
        // ---- idx prefetch for NEXT step ----
        if (kt + 1 < DD / BK) {
            const int rbn = chunk0 + (kt + 1) * 16 + lr_half;
            #pragma unroll
            for (int p = 0; p < 8; ++p) idxc[p] = imb[rbn + p * 2];
        }

        const ushort* At = &ldsA[cur][0];
        const ushort* Bt = &ldsB[cur][0];
        bf16x8 a[2][2], b[4][2];
        #pragma unroll
        for (int i = 0; i < 2; ++i) {
            int r = wm + i * 16 + l15;
            #pragma unroll
            for (int ks = 0; ks < 2; ++ks) {
                int sl = (ks * 4 + l4) ^ (r & 7);
                a[i][ks] = *(const bf16x8*)&At[r * 64 + sl * 8];
            }
        }
        #pragma unroll
        for (int j = 0; j < 4; ++j) {
            int r = wn + j * 16 + l15;
            #pragma unroll
            for (int ks = 0; ks < 2; ++ks) {
                int sl = (ks * 4 + l4) ^ (r & 7);
                b[j][ks] = *(const bf16x8*)&Bt[r * 64 + sl * 8];
            }
        }
        #pragma unroll
        for (int ks = 0; ks < 2; ++ks)
            #pragma unroll
            for (int i = 0; i < 2; ++i)
                #pragma unroll
                for (int j = 0; j < 4; ++j)
                    acc[i][j] = __builtin_amdgcn_mfma_f32_16x16x32_bf16(a[i][ks], b[j][ks], acc[i][j], 0, 0, 0);

        // ---- A-tile for next step: cvt + swizzled ds_write into buf^1 ----
        if (kt + 1 < DD / BK) stageA(cur ^ 1, kt + 1);

        __syncthreads();
        cur ^= 1;
    }
    // ---- final LR store (step 7's frames) ----
    {
        const int rbp = chunk0 + (DD / BK - 1) * 16 + lr_half;
        #pragma unroll
        for (int p = 0; p < 8; ++p)
            __builtin_nontemporal_store(gv[p], &o4[(size_t)(rbp + p * 2) * (DD / 4) + lr_lane]);
    }

    // epilogue: relu(acc + b1) dot W2; partial slice = col-block*2 + col-half
    const int pslice = (bid & 3) * 2 + (wn >> 6);
    #pragma unroll
    for (int i = 0; i < 2; ++i) {
        #pragma unroll
        for (int r = 0; r < 4; ++r) {
            float s = 0.f;
            #pragma unroll
            for (int j = 0; j < 4; ++j) {
                int cg = col0 + wn + j * 16 + l15;
                float h = acc[i][j][r] + b1[cg];
                h = fmaxf(h, 0.f);
                s += h * W2[cg];
            }
            s += __shfl_xor(s, 1);
            s += __shfl_xor(s, 2);
            s += __shfl_xor(s, 4);
            s += __shfl_xor(s, 8);
            if (l15 == 0) {
                int rg = row0 + wm + i * 16 + l4 * 4 + r;
                partial[(size_t)pslice * MM + rg] = s;
            }
        }
    }
}

// ---------------- final dpo: relu(sum of 8 partials + b2) ----------------
__global__ __launch_bounds__(256) void dpo_kernel(const float* __restrict__ partial,
                                                  const float* __restrict__ b2,
                                                  float* __restrict__ dpo) {
    int m = blockIdx.x * 256 + threadIdx.x;
    float s = b2[0];
    #pragma unroll
    for (int nb = 0; nb < NPART; ++nb) s += partial[(size_t)nb * MM + m];
    dpo[m] = fmaxf(s, 0.f);
}

extern "C" void kernel_launch(void* const* d_in, const int* in_sizes, int n_in,
                              void* d_out, int out_size, void* d_ws, size_t ws_size,
                              hipStream_t stream) {
    const float* x      = (const float*)d_in[0];
    const float* W1     = (const float*)d_in[1];
    const float* b1     = (const float*)d_in[2];
    const float* W2     = (const float*)d_in[3];
    const float* b2     = (const float*)d_in[4];
    const int*   target = (const int*)d_in[5];
    int L = (out_size - BSZ * TT) / (BSZ * DD);   // = 4096

    float* out_lr  = (float*)d_out;                        // [B, L, D]
    float* out_dpo = (float*)d_out + (size_t)BSZ * L * DD; // [B, T]

    // ws layout
    ushort* wth     = (ushort*)d_ws;                        // 512 KiB
    float*  partial = (float*)(wth + (size_t)DD * DD);      // 8*8192 floats
    int*    imap    = (int*)(partial + (size_t)NPART * MM); // 16*4096 ints

    prep_kernel<<<dim3(272), dim3(256), 0, stream>>>(W1, target, wth, imap, L);
    mega_kernel<<<dim3(NMEGA), dim3(256), 0, stream>>>(wth, b1, W2, x, imap,
                                                       out_lr, partial, L);
    dpo_kernel<<<dim3(MM / 256), dim3(256), 0, stream>>>(partial, b2, out_dpo);
}